// Round 4
// baseline (101.396 us; speedup 1.0000x reference)
//
#include <hip/hip_runtime.h>

#define NN 2048
#define AD 64
#define HH 8
#define DD 512
#define NEG 0.2f

typedef float f32x4 __attribute__((ext_vector_type(4)));
typedef _Float16 half8 __attribute__((ext_vector_type(8)));
typedef unsigned short u16;
typedef u16 u16x8 __attribute__((ext_vector_type(8)));

// ---------------------------------------------------------------------------
// Kernel 1: Q = X@Qw + Qb, K = X@Kw + Kb, VtH = f16(X@Vw + Vb)^T
// grid 384 = 3 mats x (32 row-groups x 4 col-groups), block 256
// ---------------------------------------------------------------------------
__global__ __launch_bounds__(256) void qkv_kernel(
    const float* __restrict__ X,
    const float* __restrict__ Qw, const float* __restrict__ Qb,
    const float* __restrict__ Kw, const float* __restrict__ Kb,
    const float* __restrict__ Vw, const float* __restrict__ Vb,
    float* __restrict__ Q, float* __restrict__ K, u16* __restrict__ VtH) {
  __shared__ float Xs[64][68];
  int t = threadIdx.x;
  int b = blockIdx.x;
  int m = b >> 7;           // 0:Q 1:K 2:V
  int tile = b & 127;
  int r0 = (tile >> 2) * 64;
  int d0 = (tile & 3) * 128;
  const float* W  = (m == 0) ? Qw : (m == 1) ? Kw : Vw;
  const float* Bv = (m == 0) ? Qb : (m == 1) ? Kb : Vb;

  for (int idx = t; idx < 64 * 64; idx += 256) {
    int r = idx >> 6, c = idx & 63;
    Xs[r][c] = X[(size_t)(r0 + r) * AD + c];
  }
  __syncthreads();

  int tr = t >> 5;
  int td = t & 31;
  int d = d0 + td * 4;
  float4 bias = *(const float4*)&Bv[d];
  float4 acc[8];
#pragma unroll
  for (int i = 0; i < 8; ++i) acc[i] = bias;
  for (int c = 0; c < 64; ++c) {
    float4 w = *(const float4*)&W[c * DD + d];
#pragma unroll
    for (int i = 0; i < 8; ++i) {
      float x = Xs[tr * 8 + i][c];
      acc[i].x += x * w.x; acc[i].y += x * w.y;
      acc[i].z += x * w.z; acc[i].w += x * w.w;
    }
  }
  if (m == 2) {
#pragma unroll
    for (int c = 0; c < 4; ++c) {
      u16x8 o;
#pragma unroll
      for (int i = 0; i < 8; ++i) {
        float fv = (c == 0) ? acc[i].x : (c == 1) ? acc[i].y
                 : (c == 2) ? acc[i].z : acc[i].w;
        _Float16 hf = (_Float16)fv;
        o[i] = __builtin_bit_cast(u16, hf);
      }
      *(u16x8*)&VtH[(size_t)(d + c) * NN + r0 + tr * 8] = o;
    }
  } else {
    float* O = (m == 0) ? Q : K;
#pragma unroll
    for (int i = 0; i < 8; ++i) {
      *(float4*)&O[(size_t)(r0 + tr * 8 + i) * DD + d] = acc[i];
    }
  }
}

// ---------------------------------------------------------------------------
// Kernel 2: S1[i][k*8+h], S2[j][k*8+h]. grid 512 (4 rows each), block 256.
// ---------------------------------------------------------------------------
__global__ __launch_bounds__(256) void s12_kernel(
    const float* __restrict__ Q, const float* __restrict__ K,
    const float* __restrict__ A,
    float* __restrict__ S1, float* __restrict__ S2) {
  __shared__ float Qs[4][512];
  __shared__ float Ks[4][512];
  __shared__ float red1[4][4][64];
  __shared__ float red2[4][4][64];
  int t = threadIdx.x;
  int r0 = blockIdx.x * 4;
  for (int idx = t; idx < 4 * 128; idx += 256) {
    int r = idx >> 7, dd = (idx & 127) * 4;
    *(float4*)&Qs[r][dd] = *(const float4*)&Q[(size_t)(r0 + r) * DD + dd];
    *(float4*)&Ks[r][dd] = *(const float4*)&K[(size_t)(r0 + r) * DD + dd];
  }
  __syncthreads();
  int kh = t & 63;
  int dg = t >> 6;
  int k = kh >> 3, h = kh & 7;
  float as1[4], as2[4];
#pragma unroll
  for (int i = 0; i < 4; ++i) { as1[i] = 0.f; as2[i] = 0.f; }
  const float* A1 = A + (size_t)k * 1024 * 8 + h;
  const float* A2 = A1 + 512 * 8;
  for (int dq = 0; dq < 32; ++dq) {
    int dd = dg * 128 + dq * 4;
    float a10 = A1[(dd + 0) * 8], a11 = A1[(dd + 1) * 8],
          a12 = A1[(dd + 2) * 8], a13 = A1[(dd + 3) * 8];
    float a20 = A2[(dd + 0) * 8], a21 = A2[(dd + 1) * 8],
          a22 = A2[(dd + 2) * 8], a23 = A2[(dd + 3) * 8];
#pragma unroll
    for (int i = 0; i < 4; ++i) {
      float4 q  = *(const float4*)&Qs[i][dd];
      float4 kk = *(const float4*)&Ks[i][dd];
      as1[i] += q.x  * a10 + q.y  * a11 + q.z  * a12 + q.w  * a13;
      as2[i] += kk.x * a20 + kk.y * a21 + kk.z * a22 + kk.w * a23;
    }
  }
#pragma unroll
  for (int i = 0; i < 4; ++i) {
    red1[dg][i][kh] = as1[i];
    red2[dg][i][kh] = as2[i];
  }
  __syncthreads();
  {
    int i = t >> 6, kk2 = t & 63;
    float v1 = red1[0][i][kk2] + red1[1][i][kk2] + red1[2][i][kk2] + red1[3][i][kk2];
    float v2 = red2[0][i][kk2] + red2[1][i][kk2] + red2[2][i][kk2] + red2[3][i][kk2];
    S1[(size_t)(r0 + i) * 64 + kk2] = v1;
    S2[(size_t)(r0 + i) * 64 + kk2] = v2;
  }
}

// ---------------------------------------------------------------------------
// Kernel 3: MFMA attention, barrier-free inner loop.
// grid 512 = 128 i-tiles (16 rows) x 4 j-chunks (512 j). block 512 = 8 waves.
// Wave w = head w. Lane (li = lane&15, q = lane>>4).
// S2 for a 256-j half-chunk is pre-staged in LDS (fp32), so the 4 j-tiles
// per half run with NO barriers: each wave streams independently
// (E double-buffered in regs, bfrag global loads, gather+exp, MFMA).
// Only 2 barriers per half (protect restage). LDS 76.5KB -> 2 blocks/CU.
// p scaled 1/16 into f16; denominator exact fp32.
// ---------------------------------------------------------------------------
__global__ __launch_bounds__(512, 4) void attn_mfma_kernel(
    const int* __restrict__ E,
    const float* __restrict__ S1, const float* __restrict__ S2,
    const u16* __restrict__ VtH,
    float* __restrict__ PART, float* __restrict__ LPART) {
  __shared__ float s1p[8][16][9];    // [h][i_local][k]   4.5 KB
  __shared__ float s2p[8][256][9];   // [h][j_half_local][k]  72 KB
  int t = threadIdx.x;
  int w = t >> 6, lane = t & 63;
  int li = lane & 15, q = lane >> 4;
  int bx = blockIdx.x;
  int it = bx >> 2, ch = bx & 3;
  int i0 = it * 16;
  int jch = ch * 512;

  if (t < 256) {
    int i = t >> 4, kh0 = (t & 15) * 4;
    float4 v = *(const float4*)&S1[(size_t)(i0 + i) * 64 + kh0];
    float vv[4] = {v.x, v.y, v.z, v.w};
#pragma unroll
    for (int c = 0; c < 4; ++c) {
      int kh = kh0 + c;
      s1p[kh & 7][i][kh >> 3] = vv[c];
    }
  }

  f32x4 acc[4];
#pragma unroll
  for (int n = 0; n < 4; ++n) acc[n] = (f32x4){0.f, 0.f, 0.f, 0.f};
  float lsum = 0.f;

  const int* Erow = E + (size_t)(i0 + li) * NN;
  // prefetch E for tile 0
  int4 pa0 = *(const int4*)(Erow + jch + q * 8);
  int4 pa1 = *(const int4*)(Erow + jch + q * 8 + 4);
  int4 pb0 = *(const int4*)(Erow + jch + 32 + q * 8);
  int4 pb1 = *(const int4*)(Erow + jch + 32 + q * 8 + 4);

#pragma unroll 1
  for (int half = 0; half < 2; ++half) {
    __syncthreads();   // all waves done reading previous half's s2p
    // stage s2p for this 256-j half: thread -> row j = t>>1, k-quad kp
    {
      int j = t >> 1, kp = (t & 1) * 4;   // k in [kp, kp+4)
      const float* row = &S2[(size_t)(jch + half * 256 + j) * 64 + kp * 8];
#pragma unroll
      for (int kk = 0; kk < 4; ++kk) {
        float4 u0 = *(const float4*)(row + kk * 8);
        float4 u1 = *(const float4*)(row + kk * 8 + 4);
        int k = kp + kk;
        s2p[0][j][k] = u0.x; s2p[1][j][k] = u0.y;
        s2p[2][j][k] = u0.z; s2p[3][j][k] = u0.w;
        s2p[4][j][k] = u1.x; s2p[5][j][k] = u1.y;
        s2p[6][j][k] = u1.z; s2p[7][j][k] = u1.w;
      }
    }
    __syncthreads();

    // 4 j-tiles, NO barriers inside
#pragma unroll 1
    for (int jt = 0; jt < 4; ++jt) {
      int g = half * 4 + jt;            // global tile index 0..7
      int jb = jch + g * 64;
      int jl = jt * 64;                 // half-local base in s2p

      // consume prefetched E; issue next tile's E loads early
      int4 ca0 = pa0, ca1 = pa1, cb0 = pb0, cb1 = pb1;
      if (g < 7) {
        int base = jb + 64 + q * 8;
        pa0 = *(const int4*)(Erow + base);
        pa1 = *(const int4*)(Erow + base + 4);
        pb0 = *(const int4*)(Erow + base + 32);
        pb1 = *(const int4*)(Erow + base + 32 + 4);
      }

      // B fragments (global, L2-resident VtH)
      half8 bfrag[4][2];
#pragma unroll
      for (int n = 0; n < 4; ++n)
#pragma unroll
        for (int s = 0; s < 2; ++s) {
          const u16* p = &VtH[(size_t)(w * 64 + n * 16 + li) * NN + jb + s * 32 + q * 8];
          bfrag[n][s] = *(const half8*)p;
        }

      // scores -> A fragments
      const float* s1row = &s1p[w][li][0];
      half8 af0, af1;
      {
        int ed[8] = {ca0.x, ca0.y, ca0.z, ca0.w, ca1.x, ca1.y, ca1.z, ca1.w};
        float ls = 0.f;
#pragma unroll
        for (int e = 0; e < 8; ++e) {
          int edge = ed[e];
          int k = min(max(edge, 0), 7);
          float sv = s1row[k] + s2p[w][jl + q * 8 + e][k];
          float ev = fmaxf(sv, NEG * sv);
          ev = (edge >= 0) ? ev : 0.0f;
          float pv = __expf(ev);
          ls += pv;
          af0[e] = (_Float16)(pv * 0.0625f);
        }
        lsum += ls;
      }
      {
        int ed[8] = {cb0.x, cb0.y, cb0.z, cb0.w, cb1.x, cb1.y, cb1.z, cb1.w};
        float ls = 0.f;
#pragma unroll
        for (int e = 0; e < 8; ++e) {
          int edge = ed[e];
          int k = min(max(edge, 0), 7);
          float sv = s1row[k] + s2p[w][jl + 32 + q * 8 + e][k];
          float ev = fmaxf(sv, NEG * sv);
          ev = (edge >= 0) ? ev : 0.0f;
          float pv = __expf(ev);
          ls += pv;
          af1[e] = (_Float16)(pv * 0.0625f);
        }
        lsum += ls;
      }

      // MFMA cluster (T5: setprio while on the matrix pipe)
      __builtin_amdgcn_s_setprio(1);
#pragma unroll
      for (int n = 0; n < 4; ++n) {
        acc[n] = __builtin_amdgcn_mfma_f32_16x16x32_f16(af0, bfrag[n][0], acc[n], 0, 0, 0);
        acc[n] = __builtin_amdgcn_mfma_f32_16x16x32_f16(af1, bfrag[n][1], acc[n], 0, 0, 0);
      }
      __builtin_amdgcn_s_setprio(0);
    }
  }

  // denominator: lanes {li, li+16, li+32, li+48} share row li -> reduce over q
  lsum += __shfl_xor(lsum, 16);
  lsum += __shfl_xor(lsum, 32);
  if (q == 0) {
    LPART[((size_t)ch * NN + i0 + li) * 8 + w] = lsum;
  }

  // store partial numerators. C layout: col = lane&15, row = (lane>>4)*4 + reg
  float* base = PART + (size_t)ch * NN * DD;
#pragma unroll
  for (int n = 0; n < 4; ++n) {
#pragma unroll
    for (int r = 0; r < 4; ++r) {
      int row = i0 + q * 4 + r;
      int col = w * 64 + n * 16 + li;
      base[(size_t)row * DD + col] = acc[n][r];
    }
  }
}

// ---------------------------------------------------------------------------
// Kernel 4: combine 4 j-chunk partials, divide by denominator (x16 for the
// f16 P scaling), project with Pw + Pb. grid 512 (4 rows), block 256.
// ---------------------------------------------------------------------------
__global__ __launch_bounds__(256) void proj_kernel(
    const float* __restrict__ PART, const float* __restrict__ LPART,
    const float* __restrict__ Pw, const float* __restrict__ Pb,
    float* __restrict__ out) {
  __shared__ __align__(16) float preS[4][512];
  __shared__ float linv[4][8];
  int t = threadIdx.x;
  int r0 = blockIdx.x * 4;
  if (t < 32) {
    int i = t >> 3, h = t & 7;
    float s = 0.f;
#pragma unroll
    for (int c = 0; c < 4; ++c)
      s += LPART[(size_t)c * NN * 8 + (size_t)(r0 + i) * 8 + h];
    linv[i][h] = 16.0f / s;
  }
  __syncthreads();
  for (int idx = t; idx < 4 * 128; idx += 256) {
    int i = idx >> 7, hd = (idx & 127) * 4;
    float4 v = {0.f, 0.f, 0.f, 0.f};
#pragma unroll
    for (int c = 0; c < 4; ++c) {
      float4 p = *(const float4*)&PART[(size_t)c * NN * DD + (size_t)(r0 + i) * DD + hd];
      v.x += p.x; v.y += p.y; v.z += p.z; v.w += p.w;
    }
    float li2 = linv[i][hd >> 6];
    v.x *= li2; v.y *= li2; v.z *= li2; v.w *= li2;
    *(float4*)&preS[i][hd] = v;
  }
  __syncthreads();
  int c = t & 63, rq = t >> 6;
  float acc0 = Pb[c];
  for (int hq = 0; hq < 128; ++hq) {
    int hd = hq * 4;
    float4 p0 = *(const float4*)&preS[rq][hd];
    float w0 = Pw[(hd + 0) * 64 + c];
    float w1 = Pw[(hd + 1) * 64 + c];
    float w2 = Pw[(hd + 2) * 64 + c];
    float w3 = Pw[(hd + 3) * 64 + c];
    acc0 += p0.x * w0 + p0.y * w1 + p0.z * w2 + p0.w * w3;
  }
  out[(size_t)(r0 + rq) * 64 + c] = acc0;
}

// ---------------------------------------------------------------------------
extern "C" void kernel_launch(void* const* d_in, const int* in_sizes, int n_in,
                              void* d_out, int out_size, void* d_ws, size_t ws_size,
                              hipStream_t stream) {
  const float* X  = (const float*)d_in[0];
  const int*   E  = (const int*)d_in[1];
  const float* Qw = (const float*)d_in[2];
  const float* Qb = (const float*)d_in[3];
  const float* Kw = (const float*)d_in[4];
  const float* Kb = (const float*)d_in[5];
  const float* Vw = (const float*)d_in[6];
  const float* Vb = (const float*)d_in[7];
  const float* A  = (const float*)d_in[8];
  const float* Pw = (const float*)d_in[9];
  const float* Pb = (const float*)d_in[10];
  float* out = (float*)d_out;

  float* ws = (float*)d_ws;
  const size_t ND = (size_t)NN * DD;            // 1M floats
  float* Q     = ws;                            // [0, 1M)
  float* K     = ws + ND;                       // [1M, 2M)
  float* PART  = ws;                            // [0, 4M) (aliases Q/K, dead)
  float* S1    = ws + 4 * ND;                   // 128K
  float* S2    = S1 + (size_t)NN * 64;          // 128K
  u16*   VtH   = (u16*)(S2 + (size_t)NN * 64);  // 1M u16
  float* LPART = (float*)(VtH + (size_t)DD * NN); // 64K floats

  qkv_kernel<<<384, 256, 0, stream>>>(X, Qw, Qb, Kw, Kb, Vw, Vb, Q, K, VtH);
  s12_kernel<<<512, 256, 0, stream>>>(Q, K, A, S1, S2);
  attn_mfma_kernel<<<512, 512, 0, stream>>>(E, S1, S2, VtH, PART, LPART);
  proj_kernel<<<512, 256, 0, stream>>>(PART, LPART, Pw, Pb, out);
}

// Round 5
// 84.269 us; speedup vs baseline: 1.2032x; 1.2032x over previous
//
#include <hip/hip_runtime.h>

#define NN 2048
#define AD 64
#define HH 8
#define DD 512
#define NEG 0.2f

typedef float f32x4 __attribute__((ext_vector_type(4)));
typedef _Float16 half8 __attribute__((ext_vector_type(8)));
typedef _Float16 half2v __attribute__((ext_vector_type(2)));
typedef unsigned short u16;
typedef u16 u16x8 __attribute__((ext_vector_type(8)));

// ---------------------------------------------------------------------------
// Kernel 1: Q = X@Qw + Qb, K = X@Kw + Kb, VtH = f16(X@Vw + Vb)^T
// grid 384 = 3 mats x (32 row-groups x 4 col-groups), block 256
// ---------------------------------------------------------------------------
__global__ __launch_bounds__(256) void qkv_kernel(
    const float* __restrict__ X,
    const float* __restrict__ Qw, const float* __restrict__ Qb,
    const float* __restrict__ Kw, const float* __restrict__ Kb,
    const float* __restrict__ Vw, const float* __restrict__ Vb,
    float* __restrict__ Q, float* __restrict__ K, u16* __restrict__ VtH) {
  __shared__ float Xs[64][68];
  int t = threadIdx.x;
  int b = blockIdx.x;
  int m = b >> 7;           // 0:Q 1:K 2:V
  int tile = b & 127;
  int r0 = (tile >> 2) * 64;
  int d0 = (tile & 3) * 128;
  const float* W  = (m == 0) ? Qw : (m == 1) ? Kw : Vw;
  const float* Bv = (m == 0) ? Qb : (m == 1) ? Kb : Vb;

  for (int idx = t; idx < 64 * 64; idx += 256) {
    int r = idx >> 6, c = idx & 63;
    Xs[r][c] = X[(size_t)(r0 + r) * AD + c];
  }
  __syncthreads();

  int tr = t >> 5;
  int td = t & 31;
  int d = d0 + td * 4;
  float4 bias = *(const float4*)&Bv[d];
  float4 acc[8];
#pragma unroll
  for (int i = 0; i < 8; ++i) acc[i] = bias;
  for (int c = 0; c < 64; ++c) {
    float4 w = *(const float4*)&W[c * DD + d];
#pragma unroll
    for (int i = 0; i < 8; ++i) {
      float x = Xs[tr * 8 + i][c];
      acc[i].x += x * w.x; acc[i].y += x * w.y;
      acc[i].z += x * w.z; acc[i].w += x * w.w;
    }
  }
  if (m == 2) {
#pragma unroll
    for (int c = 0; c < 4; ++c) {
      u16x8 o;
#pragma unroll
      for (int i = 0; i < 8; ++i) {
        float fv = (c == 0) ? acc[i].x : (c == 1) ? acc[i].y
                 : (c == 2) ? acc[i].z : acc[i].w;
        _Float16 hf = (_Float16)fv;
        o[i] = __builtin_bit_cast(u16, hf);
      }
      *(u16x8*)&VtH[(size_t)(d + c) * NN + r0 + tr * 8] = o;
    }
  } else {
    float* O = (m == 0) ? Q : K;
#pragma unroll
    for (int i = 0; i < 8; ++i) {
      *(float4*)&O[(size_t)(r0 + tr * 8 + i) * DD + d] = acc[i];
    }
  }
}

// ---------------------------------------------------------------------------
// Kernel 2: S1[i][k*8+h], S2[j][k*8+h]. grid 512 (4 rows each), block 256.
// ---------------------------------------------------------------------------
__global__ __launch_bounds__(256) void s12_kernel(
    const float* __restrict__ Q, const float* __restrict__ K,
    const float* __restrict__ A,
    float* __restrict__ S1, float* __restrict__ S2) {
  __shared__ float Qs[4][512];
  __shared__ float Ks[4][512];
  __shared__ float red1[4][4][64];
  __shared__ float red2[4][4][64];
  int t = threadIdx.x;
  int r0 = blockIdx.x * 4;
  for (int idx = t; idx < 4 * 128; idx += 256) {
    int r = idx >> 7, dd = (idx & 127) * 4;
    *(float4*)&Qs[r][dd] = *(const float4*)&Q[(size_t)(r0 + r) * DD + dd];
    *(float4*)&Ks[r][dd] = *(const float4*)&K[(size_t)(r0 + r) * DD + dd];
  }
  __syncthreads();
  int kh = t & 63;
  int dg = t >> 6;
  int k = kh >> 3, h = kh & 7;
  float as1[4], as2[4];
#pragma unroll
  for (int i = 0; i < 4; ++i) { as1[i] = 0.f; as2[i] = 0.f; }
  const float* A1 = A + (size_t)k * 1024 * 8 + h;
  const float* A2 = A1 + 512 * 8;
  for (int dq = 0; dq < 32; ++dq) {
    int dd = dg * 128 + dq * 4;
    float a10 = A1[(dd + 0) * 8], a11 = A1[(dd + 1) * 8],
          a12 = A1[(dd + 2) * 8], a13 = A1[(dd + 3) * 8];
    float a20 = A2[(dd + 0) * 8], a21 = A2[(dd + 1) * 8],
          a22 = A2[(dd + 2) * 8], a23 = A2[(dd + 3) * 8];
#pragma unroll
    for (int i = 0; i < 4; ++i) {
      float4 q  = *(const float4*)&Qs[i][dd];
      float4 kk = *(const float4*)&Ks[i][dd];
      as1[i] += q.x  * a10 + q.y  * a11 + q.z  * a12 + q.w  * a13;
      as2[i] += kk.x * a20 + kk.y * a21 + kk.z * a22 + kk.w * a23;
    }
  }
#pragma unroll
  for (int i = 0; i < 4; ++i) {
    red1[dg][i][kh] = as1[i];
    red2[dg][i][kh] = as2[i];
  }
  __syncthreads();
  {
    int i = t >> 6, kk2 = t & 63;
    float v1 = red1[0][i][kk2] + red1[1][i][kk2] + red1[2][i][kk2] + red1[3][i][kk2];
    float v2 = red2[0][i][kk2] + red2[1][i][kk2] + red2[2][i][kk2] + red2[3][i][kk2];
    S1[(size_t)(r0 + i) * 64 + kk2] = v1;
    S2[(size_t)(r0 + i) * 64 + kk2] = v2;
  }
}

// ---------------------------------------------------------------------------
// Kernel 3: MFMA attention, vectorized-over-h scoring.
// grid 512 = 128 i-tiles (16 rows) x 4 j-chunks (512 j). block 512 = 8 waves.
// Per 64-j tile, two phases, ONE barrier:
//  Phase A (thread = (i_loc = w*2 + lane>>5, j = 2m,2m+1)): k = E[i][j];
//    all-8-head S1/S2 fetched as 2+2 ds_read_b128 (natural [row][k*8+h]
//    layout); 8 exp chains; f16 pairs packed into PA[h][i][j] (b32 writes).
//    lsum[h] accumulated per thread (fp32 exact).
//  Phase B (wave = head w): afrag = one b128 from PA[w][li][s*32+q*8];
//    bfrag = VtH global loads issued BEFORE phase A (latency hidden);
//    8 MFMAs into acc.
// PA and s2 staging double-buffered -> 1 barrier/tile. LDS 76KB, 2 blk/CU.
// p scaled 1/16 into f16; restored in proj. Same verified MFMA layouts.
// ---------------------------------------------------------------------------
__global__ __launch_bounds__(512, 4) void attn_mfma_kernel(
    const int* __restrict__ E,
    const float* __restrict__ S1, const float* __restrict__ S2,
    const u16* __restrict__ VtH,
    float* __restrict__ PART, float* __restrict__ LPART) {
  __shared__ float s1p[16][68];            // natural [i][k*8+h], 4.35 KB
  __shared__ float s2b[2][64][68];         // natural [j][k*8+h], 34.8 KB
  __shared__ _Float16 PA[2][8][16][72];    // [h][i][j], 36.9 KB
  int t = threadIdx.x;
  int w = t >> 6, lane = t & 63;
  int li = lane & 15, q = lane >> 4;
  int m = lane & 31;
  int i_loc = w * 2 + (lane >> 5);
  int bx = blockIdx.x;
  int it = bx >> 2, ch = bx & 3;
  int i0 = it * 16, jch = ch * 512;

  // stage s1p (16 rows x 64 floats)
  if (t < 256) {
    int i = t >> 4, c = (t & 15) * 4;
    *(float4*)&s1p[i][c] = *(const float4*)&S1[(size_t)(i0 + i) * 64 + c];
  }
  // stage s2b[0] for tile 0
#pragma unroll
  for (int u = 0; u < 2; ++u) {
    int idx = t + u * 512;
    int j = idx >> 4, c = (idx & 15) * 4;
    *(float4*)&s2b[0][j][c] = *(const float4*)&S2[(size_t)(jch + j) * 64 + c];
  }
  const int* Erow = E + (size_t)(i0 + i_loc) * NN;
  int2 ecur = *(const int2*)(Erow + jch + 2 * m);
  __syncthreads();

  f32x4 acc[4];
#pragma unroll
  for (int n = 0; n < 4; ++n) acc[n] = (f32x4){0.f, 0.f, 0.f, 0.f};
  float lsum[8];
#pragma unroll
  for (int h = 0; h < 8; ++h) lsum[h] = 0.f;
  int cur = 0;

#pragma unroll 1
  for (int jt = 0; jt < 8; ++jt) {
    int jb = jch + jt * 64;

    // stage next tile's s2 + E (into the other buffer / regs)
    int2 enxt = ecur;
    if (jt < 7) {
      enxt = *(const int2*)(Erow + jb + 64 + 2 * m);
#pragma unroll
      for (int u = 0; u < 2; ++u) {
        int idx = t + u * 512;
        int j = idx >> 4, c = (idx & 15) * 4;
        *(float4*)&s2b[cur ^ 1][j][c] =
            *(const float4*)&S2[(size_t)(jb + 64 + j) * 64 + c];
      }
    }

    // bfrag loads for THIS tile (global/L2) -- latency hides under phase A
    half8 bfrag[4][2];
#pragma unroll
    for (int n = 0; n < 4; ++n)
#pragma unroll
      for (int s = 0; s < 2; ++s) {
        const u16* p = &VtH[(size_t)(w * 64 + n * 16 + li) * NN + jb + s * 32 + q * 8];
        bfrag[n][s] = *(const half8*)p;
      }

    // ---- Phase A: scores for (i_loc, j=2m) and (i_loc, j=2m+1), all 8 h
    _Float16 pv0[8], pv1[8];
#pragma unroll
    for (int jj = 0; jj < 2; ++jj) {
      int ev = jj ? ecur.y : ecur.x;
      int j = 2 * m + jj;
      int k = min(max(ev, 0), 7);
      f32x4 a0 = *(const f32x4*)&s1p[i_loc][k * 8];
      f32x4 a1 = *(const f32x4*)&s1p[i_loc][k * 8 + 4];
      f32x4 b0 = *(const f32x4*)&s2b[cur][j][k * 8];
      f32x4 b1 = *(const f32x4*)&s2b[cur][j][k * 8 + 4];
      bool valid = ev >= 0;
      float sarr[8];
#pragma unroll
      for (int h = 0; h < 4; ++h) { sarr[h] = a0[h] + b0[h]; sarr[h + 4] = a1[h] + b1[h]; }
#pragma unroll
      for (int h = 0; h < 8; ++h) {
        float s = sarr[h];
        float e = fmaxf(s, NEG * s);
        e = valid ? e : 0.0f;
        float p = __expf(e);
        lsum[h] += p;
        _Float16 pf = (_Float16)(p * 0.0625f);
        if (jj == 0) pv0[h] = pf; else pv1[h] = pf;
      }
    }
    // packed f16-pair writes PA[h][i_loc][2m]
#pragma unroll
    for (int h = 0; h < 8; ++h) {
      half2v pr = {pv0[h], pv1[h]};
      *(half2v*)&PA[cur][h][i_loc][2 * m] = pr;
    }
    __syncthreads();

    // ---- Phase B: afrag from PA, MFMA
    half8 af0 = *(const half8*)&PA[cur][w][li][q * 8];
    half8 af1 = *(const half8*)&PA[cur][w][li][32 + q * 8];
    __builtin_amdgcn_s_setprio(1);
#pragma unroll
    for (int n = 0; n < 4; ++n) {
      acc[n] = __builtin_amdgcn_mfma_f32_16x16x32_f16(af0, bfrag[n][0], acc[n], 0, 0, 0);
      acc[n] = __builtin_amdgcn_mfma_f32_16x16x32_f16(af1, bfrag[n][1], acc[n], 0, 0, 0);
    }
    __builtin_amdgcn_s_setprio(0);

    ecur = enxt;
    cur ^= 1;
  }

  // lsum: reduce over the 32 lanes sharing i_loc (m dimension)
#pragma unroll
  for (int h = 0; h < 8; ++h) {
    float v = lsum[h];
    v += __shfl_xor(v, 1);  v += __shfl_xor(v, 2);  v += __shfl_xor(v, 4);
    v += __shfl_xor(v, 8);  v += __shfl_xor(v, 16);
    lsum[h] = v;
  }
  if (m == 0) {
    float* lp = &LPART[((size_t)ch * NN + i0 + i_loc) * 8];
#pragma unroll
    for (int h = 0; h < 8; ++h) lp[h] = lsum[h];
  }

  // store partial numerators. C layout: col = lane&15, row = (lane>>4)*4 + reg
  float* base = PART + (size_t)ch * NN * DD;
#pragma unroll
  for (int n = 0; n < 4; ++n) {
#pragma unroll
    for (int r = 0; r < 4; ++r) {
      int row = i0 + q * 4 + r;
      int col = w * 64 + n * 16 + li;
      base[(size_t)row * DD + col] = acc[n][r];
    }
  }
}

// ---------------------------------------------------------------------------
// Kernel 4: combine 4 j-chunk partials, divide by denominator (x16 for the
// f16 P scaling), project with Pw + Pb. grid 512 (4 rows), block 256.
// ---------------------------------------------------------------------------
__global__ __launch_bounds__(256) void proj_kernel(
    const float* __restrict__ PART, const float* __restrict__ LPART,
    const float* __restrict__ Pw, const float* __restrict__ Pb,
    float* __restrict__ out) {
  __shared__ __align__(16) float preS[4][512];
  __shared__ float linv[4][8];
  int t = threadIdx.x;
  int r0 = blockIdx.x * 4;
  if (t < 32) {
    int i = t >> 3, h = t & 7;
    float s = 0.f;
#pragma unroll
    for (int c = 0; c < 4; ++c)
      s += LPART[(size_t)c * NN * 8 + (size_t)(r0 + i) * 8 + h];
    linv[i][h] = 16.0f / s;
  }
  __syncthreads();
  for (int idx = t; idx < 4 * 128; idx += 256) {
    int i = idx >> 7, hd = (idx & 127) * 4;
    float4 v = {0.f, 0.f, 0.f, 0.f};
#pragma unroll
    for (int c = 0; c < 4; ++c) {
      float4 p = *(const float4*)&PART[(size_t)c * NN * DD + (size_t)(r0 + i) * DD + hd];
      v.x += p.x; v.y += p.y; v.z += p.z; v.w += p.w;
    }
    float li2 = linv[i][hd >> 6];
    v.x *= li2; v.y *= li2; v.z *= li2; v.w *= li2;
    *(float4*)&preS[i][hd] = v;
  }
  __syncthreads();
  int c = t & 63, rq = t >> 6;
  float acc0 = Pb[c];
  for (int hq = 0; hq < 128; ++hq) {
    int hd = hq * 4;
    float4 p0 = *(const float4*)&preS[rq][hd];
    float w0 = Pw[(hd + 0) * 64 + c];
    float w1 = Pw[(hd + 1) * 64 + c];
    float w2 = Pw[(hd + 2) * 64 + c];
    float w3 = Pw[(hd + 3) * 64 + c];
    acc0 += p0.x * w0 + p0.y * w1 + p0.z * w2 + p0.w * w3;
  }
  out[(size_t)(r0 + rq) * 64 + c] = acc0;
}

// ---------------------------------------------------------------------------
extern "C" void kernel_launch(void* const* d_in, const int* in_sizes, int n_in,
                              void* d_out, int out_size, void* d_ws, size_t ws_size,
                              hipStream_t stream) {
  const float* X  = (const float*)d_in[0];
  const int*   E  = (const int*)d_in[1];
  const float* Qw = (const float*)d_in[2];
  const float* Qb = (const float*)d_in[3];
  const float* Kw = (const float*)d_in[4];
  const float* Kb = (const float*)d_in[5];
  const float* Vw = (const float*)d_in[6];
  const float* Vb = (const float*)d_in[7];
  const float* A  = (const float*)d_in[8];
  const float* Pw = (const float*)d_in[9];
  const float* Pb = (const float*)d_in[10];
  float* out = (float*)d_out;

  float* ws = (float*)d_ws;
  const size_t ND = (size_t)NN * DD;            // 1M floats
  float* Q     = ws;                            // [0, 1M)
  float* K     = ws + ND;                       // [1M, 2M)
  float* PART  = ws;                            // [0, 4M) (aliases Q/K, dead)
  float* S1    = ws + 4 * ND;                   // 128K
  float* S2    = S1 + (size_t)NN * 64;          // 128K
  u16*   VtH   = (u16*)(S2 + (size_t)NN * 64);  // 1M u16
  float* LPART = (float*)(VtH + (size_t)DD * NN); // 64K floats

  qkv_kernel<<<384, 256, 0, stream>>>(X, Qw, Qb, Kw, Kb, Vw, Vb, Q, K, VtH);
  s12_kernel<<<512, 256, 0, stream>>>(Q, K, A, S1, S2);
  attn_mfma_kernel<<<512, 512, 0, stream>>>(E, S1, S2, VtH, PART, LPART);
  proj_kernel<<<512, 256, 0, stream>>>(PART, LPART, Pw, Pb, out);
}